// Round 7
// baseline (202.146 us; speedup 1.0000x reference)
//
#include <hip/hip_runtime.h>
#include <hip/hip_fp16.h>

typedef _Float16 f16;
typedef _Float16 f16x8 __attribute__((ext_vector_type(8)));
typedef _Float16 f16x4 __attribute__((ext_vector_type(4)));
typedef float f32x4 __attribute__((ext_vector_type(4)));

#define LN_EPS 1e-5f

// erf via Abramowitz-Stegun 7.1.26 (|eps| <= 1.5e-7)
__device__ __forceinline__ float erf_fast(float x) {
    const float ax = __builtin_fabsf(x);
    const float t = 1.0f / (1.0f + 0.3275911f * ax);
    const float y = t * (0.254829592f +
                    t * (-0.284496736f +
                    t * (1.421413741f +
                    t * (-1.453152027f +
                    t * 1.061405429f))));
    const float r = 1.0f - y * __expf(-ax * ax);
    return __builtin_copysignf(r, x);
}

__device__ __forceinline__ float gelu_exact(float v) {
    return 0.5f * v * (1.0f + erf_fast(v * 0.70710678118654752440f));
}

// async global -> LDS, 16B per lane; lds dest is wave-uniform base (+lane*16 by HW)
__device__ __forceinline__ void gload_lds16(const f16* g, f16* l) {
    __builtin_amdgcn_global_load_lds(
        (const __attribute__((address_space(1))) unsigned int*)(g),
        (__attribute__((address_space(3))) unsigned int*)(l),
        16, 0, 0);
}

// ---------------- LayerNorm(x) -> y_h (fp16), plus x -> x_h (fp16) ----------
__global__ __launch_bounds__(256)
void ln_cast_kernel(const float* __restrict__ x,
                    const float* __restrict__ gamma,
                    const float* __restrict__ beta,
                    f16* __restrict__ y_h,
                    f16* __restrict__ x_h) {
    const int row = blockIdx.x;
    const int t = threadIdx.x;
    const size_t base = (size_t)row * 1024;
    float4 v = ((const float4*)(x + base))[t];
    float s  = v.x + v.y + v.z + v.w;
    float s2 = v.x*v.x + v.y*v.y + v.z*v.z + v.w*v.w;
    #pragma unroll
    for (int off = 32; off > 0; off >>= 1) {
        s  += __shfl_down(s, off, 64);
        s2 += __shfl_down(s2, off, 64);
    }
    __shared__ float ls[4], ls2[4];
    const int wid = t >> 6;
    if ((t & 63) == 0) { ls[wid] = s; ls2[wid] = s2; }
    __syncthreads();
    if (t == 0) {
        ls[0]  = ls[0] + ls[1] + ls[2] + ls[3];
        ls2[0] = ls2[0] + ls2[1] + ls2[2] + ls2[3];
    }
    __syncthreads();
    const float mu   = ls[0] * (1.0f / 1024.0f);
    const float var  = ls2[0] * (1.0f / 1024.0f) - mu * mu;
    const float rstd = rsqrtf(var + LN_EPS);
    const float4 g  = ((const float4*)gamma)[t];
    const float4 bt = ((const float4*)beta)[t];
    f16x4 yo, xo;
    yo[0] = (f16)((v.x - mu) * rstd * g.x + bt.x);
    yo[1] = (f16)((v.y - mu) * rstd * g.y + bt.y);
    yo[2] = (f16)((v.z - mu) * rstd * g.z + bt.z);
    yo[3] = (f16)((v.w - mu) * rstd * g.w + bt.w);
    xo[0] = (f16)v.x; xo[1] = (f16)v.y; xo[2] = (f16)v.z; xo[3] = (f16)v.w;
    *(f16x4*)(y_h + base + t * 4) = yo;
    *(f16x4*)(x_h + base + t * 4) = xo;
}

// ---------------- final LayerNorm: pre (fp32) -> out (fp32) ----------------
__global__ __launch_bounds__(256)
void ln_final_kernel(const float* __restrict__ pre,
                     const float* __restrict__ gamma,
                     const float* __restrict__ beta,
                     float* __restrict__ out) {
    const int row = blockIdx.x;
    const int t = threadIdx.x;
    const size_t base = (size_t)row * 1024;
    float4 v = ((const float4*)(pre + base))[t];
    float s  = v.x + v.y + v.z + v.w;
    float s2 = v.x*v.x + v.y*v.y + v.z*v.z + v.w*v.w;
    #pragma unroll
    for (int off = 32; off > 0; off >>= 1) {
        s  += __shfl_down(s, off, 64);
        s2 += __shfl_down(s2, off, 64);
    }
    __shared__ float ls[4], ls2[4];
    const int wid = t >> 6;
    if ((t & 63) == 0) { ls[wid] = s; ls2[wid] = s2; }
    __syncthreads();
    if (t == 0) {
        ls[0]  = ls[0] + ls[1] + ls[2] + ls[3];
        ls2[0] = ls2[0] + ls2[1] + ls2[2] + ls2[3];
    }
    __syncthreads();
    const float mu   = ls[0] * (1.0f / 1024.0f);
    const float var  = ls2[0] * (1.0f / 1024.0f) - mu * mu;
    const float rstd = rsqrtf(var + LN_EPS);
    const float4 g  = ((const float4*)gamma)[t];
    const float4 bt = ((const float4*)beta)[t];
    float4 o;
    o.x = (v.x - mu) * rstd * g.x + bt.x;
    o.y = (v.y - mu) * rstd * g.y + bt.y;
    o.z = (v.z - mu) * rstd * g.z + bt.z;
    o.w = (v.w - mu) * rstd * g.w + bt.w;
    ((float4*)(out + base))[t] = o;
}

// ------------- transpose + cast fp32 [R,C] -> fp16 [C,R] -------------------
__global__ __launch_bounds__(256)
void transpose_cast_kernel(const float* __restrict__ src,
                           f16* __restrict__ dst, int R, int C) {
    __shared__ float tile[32][33];
    const int c0 = blockIdx.x * 32, r0 = blockIdx.y * 32;
    const int tx = threadIdx.x & 31, ty = threadIdx.x >> 5;
    #pragma unroll
    for (int i = 0; i < 4; ++i) {
        const int r = ty + i * 8;
        tile[r][tx] = src[(size_t)(r0 + r) * C + c0 + tx];
    }
    __syncthreads();
    #pragma unroll
    for (int i = 0; i < 4; ++i) {
        const int r = ty + i * 8;
        dst[(size_t)(c0 + r) * R + r0 + tx] = (f16)tile[tx][r];
    }
}

// ------------- batched transpose fp16 [R,C] -> fp16 [C,R] ------------------
__global__ __launch_bounds__(256)
void transpose_f16_kernel(const f16* __restrict__ src,
                          f16* __restrict__ dst, int R, int C) {
    __shared__ f16 tile[32][33];
    const size_t zb = (size_t)blockIdx.z * R * C;
    src += zb; dst += zb;
    const int c0 = blockIdx.x * 32, r0 = blockIdx.y * 32;
    const int tx = threadIdx.x & 31, ty = threadIdx.x >> 5;
    #pragma unroll
    for (int i = 0; i < 4; ++i) {
        const int r = ty + i * 8;
        tile[r][tx] = src[(size_t)(r0 + r) * C + c0 + tx];
    }
    __syncthreads();
    #pragma unroll
    for (int i = 0; i < 4; ++i) {
        const int r = ty + i * 8;
        dst[(size_t)(c0 + r) * R + r0 + tx] = tile[tx][r];
    }
}

// ====== 256x128 8-wave GEMM (NT), BK=64, ring-3 LDS, 4 phases/K-tile =======
// Wave grid 4(M) x 2(N), wave tile 64x64. LDS: A 3x32KB + B 3x16KB = 144KB.
// Ring-3 + counted vmcnt(6): no intra-tile barriers -> waves drift, ds_read
// of one wave overlaps MFMA of another (no LDS<->MFMA lockstep serialization).
// Swizzle: 16B slot s of row r holds k-slot s^(r&7); pre-swizzled global src.
// SWAP (EPI != 1): mfma(b,a) so acc reg index walks N -> vectorized
// f16x4/float4 epilogue stores along the row.
// EPI: 0 = +bias, gelu, fp16 out [M][N]               (swapped)
//      1 = +bias, fp16 out transposed per batch [z][col][row%2048] (unswapped)
//      3 = fp32 out + xadd (batched via blockIdx.z)   (swapped)
template <int EPI>
__global__ __launch_bounds__(512, 2)
void gemm256x128_nt_kernel(const f16* __restrict__ A, const f16* __restrict__ Bt,
                           const float* __restrict__ bias,
                           const float* __restrict__ xadd,
                           f16* __restrict__ outH, float* __restrict__ outF,
                           int M, int N, int K,
                           long long batchA, long long batchB, long long batchC) {
    __shared__ __attribute__((aligned(16))) f16 sA[3][256 * 64];
    __shared__ __attribute__((aligned(16))) f16 sB[3][128 * 64];

    const int z = blockIdx.z;
    A  += (size_t)z * batchA;
    Bt += (size_t)z * batchB;

    const int m0 = blockIdx.x * 256;
    const int n0 = blockIdx.y * 128;
    const int t = threadIdx.x;
    const int l = t & 63;
    const int wid = t >> 6;
    const int wr = wid >> 1;      // 0-3 (M)
    const int wc = wid & 1;       // 0-1 (N)
    const int rl = l & 15;
    const int g  = l >> 4;        // 0-3
    const int nk = K >> 6;

    // staging: unit = 512 lanes x 16B = 64 rows x 64 f16. thread t covers
    // row (t>>3) within unit, slot t&7; source k-slot = slot ^ (row&7).
    const int rowS = t >> 3;                       // 0..63
    const int kbS  = ((t & 7) ^ (rowS & 7)) * 8;
    const f16* pA = A  + (size_t)(m0 + rowS) * K + kbS;
    const f16* pB = Bt + (size_t)(n0 + rowS) * K + kbS;
    const int ldsS = wid * 512;   // wave-uniform base within unit (HW +lane*16B)

    const int rA = wr * 64 + rl;
    const int rB = wc * 64 + rl;
    const int swk0 = ((g)     ^ (rl & 7)) * 8;
    const int swk1 = ((4 + g) ^ (rl & 7)) * 8;

    f32x4 acc[4][4] = {};

    auto mf = [&](f32x4 c, f16x8 af, f16x8 bf) {
        if constexpr (EPI != 1)
            return __builtin_amdgcn_mfma_f32_16x16x32_f16(bf, af, c, 0, 0, 0);
        else
            return __builtin_amdgcn_mfma_f32_16x16x32_f16(af, bf, c, 0, 0, 0);
    };

    auto stgA = [&](f16* dst, int u, int kc) {   // u = 0..3
        gload_lds16(pA + (size_t)u * 64 * K + kc * 64, dst + u * 4096 + ldsS);
    };
    auto stgB = [&](f16* dst, int u, int kc) {   // u = 0..1
        gload_lds16(pB + (size_t)u * 64 * K + kc * 64, dst + u * 4096 + ldsS);
    };

    // prologue: tiles 0 and 1 (12 units outstanding)
    const int t1 = (nk > 1) ? 1 : 0;
    #pragma unroll
    for (int u = 0; u < 4; ++u) stgA(sA[0], u, 0);
    #pragma unroll
    for (int u = 0; u < 2; ++u) stgB(sB[0], u, 0);
    #pragma unroll
    for (int u = 0; u < 4; ++u) stgA(sA[1], u, t1);
    #pragma unroll
    for (int u = 0; u < 2; ++u) stgB(sB[1], u, t1);

    f16 *curA = sA[0], *nxtA = sA[1], *farA = sA[2];
    f16 *curB = sB[0], *nxtB = sB[1], *farB = sB[2];

    f16x8 a[4][2], b[4][2];

    for (int kt = 0; kt < nk; ++kt) {
        // tile kt landed for this wave; kt+1's 6 units stay in flight
        asm volatile("s_waitcnt vmcnt(6)" ::: "memory");
        __builtin_amdgcn_s_barrier();

        const int kt2 = (kt + 2 < nk) ? kt + 2 : nk - 1;

        // P0: rd a01+b01, stg A-units 0,1 of kt+2; MFMA fm01 x fn01
        #pragma unroll
        for (int fm = 0; fm < 2; ++fm) {
            a[fm][0] = *(const f16x8*)(curA + (rA + fm * 16) * 64 + swk0);
            a[fm][1] = *(const f16x8*)(curA + (rA + fm * 16) * 64 + swk1);
        }
        #pragma unroll
        for (int fn = 0; fn < 2; ++fn) {
            b[fn][0] = *(const f16x8*)(curB + (rB + fn * 16) * 64 + swk0);
            b[fn][1] = *(const f16x8*)(curB + (rB + fn * 16) * 64 + swk1);
        }
        stgA(farA, 0, kt2);
        stgA(farA, 1, kt2);
        asm volatile("s_waitcnt lgkmcnt(0)" ::: "memory");
        __builtin_amdgcn_sched_barrier(0);
        __builtin_amdgcn_s_setprio(1);
        #pragma unroll
        for (int fm = 0; fm < 2; ++fm)
            #pragma unroll
            for (int fn = 0; fn < 2; ++fn) {
                acc[fm][fn] = mf(acc[fm][fn], a[fm][0], b[fn][0]);
                acc[fm][fn] = mf(acc[fm][fn], a[fm][1], b[fn][1]);
            }
        __builtin_amdgcn_s_setprio(0);

        // P1: rd b23, stg A-units 2,3; MFMA fm01 x fn23
        #pragma unroll
        for (int fn = 2; fn < 4; ++fn) {
            b[fn][0] = *(const f16x8*)(curB + (rB + fn * 16) * 64 + swk0);
            b[fn][1] = *(const f16x8*)(curB + (rB + fn * 16) * 64 + swk1);
        }
        stgA(farA, 2, kt2);
        stgA(farA, 3, kt2);
        asm volatile("s_waitcnt lgkmcnt(0)" ::: "memory");
        __builtin_amdgcn_sched_barrier(0);
        __builtin_amdgcn_s_setprio(1);
        #pragma unroll
        for (int fm = 0; fm < 2; ++fm)
            #pragma unroll
            for (int fn = 2; fn < 4; ++fn) {
                acc[fm][fn] = mf(acc[fm][fn], a[fm][0], b[fn][0]);
                acc[fm][fn] = mf(acc[fm][fn], a[fm][1], b[fn][1]);
            }
        __builtin_amdgcn_s_setprio(0);

        // P2: rd a23, stg B-units 0,1; MFMA fm23 x fn23
        #pragma unroll
        for (int fm = 2; fm < 4; ++fm) {
            a[fm][0] = *(const f16x8*)(curA + (rA + fm * 16) * 64 + swk0);
            a[fm][1] = *(const f16x8*)(curA + (rA + fm * 16) * 64 + swk1);
        }
        stgB(farB, 0, kt2);
        stgB(farB, 1, kt2);
        asm volatile("s_waitcnt lgkmcnt(0)" ::: "memory");
        __builtin_amdgcn_sched_barrier(0);
        __builtin_amdgcn_s_setprio(1);
        #pragma unroll
        for (int fm = 2; fm < 4; ++fm)
            #pragma unroll
            for (int fn = 2; fn < 4; ++fn) {
                acc[fm][fn] = mf(acc[fm][fn], a[fm][0], b[fn][0]);
                acc[fm][fn] = mf(acc[fm][fn], a[fm][1], b[fn][1]);
            }
        __builtin_amdgcn_s_setprio(0);

        // P3: MFMA fm23 x fn01 (all operands in regs)
        __builtin_amdgcn_s_setprio(1);
        #pragma unroll
        for (int fm = 2; fm < 4; ++fm)
            #pragma unroll
            for (int fn = 0; fn < 2; ++fn) {
                acc[fm][fn] = mf(acc[fm][fn], a[fm][0], b[fn][0]);
                acc[fm][fn] = mf(acc[fm][fn], a[fm][1], b[fn][1]);
            }
        __builtin_amdgcn_s_setprio(0);

        // rotate ring
        f16* tp;
        tp = curA; curA = nxtA; nxtA = farA; farA = tp;
        tp = curB; curB = nxtB; nxtB = farB; farB = tp;
    }
    asm volatile("s_waitcnt vmcnt(0)" ::: "memory");

    // ---------------- epilogue ----------------
    if (EPI == 1) {
        // unswapped: reg r walks M (=T) -> f16x4 along T in transposed out
        #pragma unroll
        for (int fm = 0; fm < 4; ++fm) {
            #pragma unroll
            for (int fn = 0; fn < 4; ++fn) {
                const int col = n0 + wc * 64 + fn * 16 + rl;
                const int row0 = m0 + wr * 64 + fm * 16 + g * 4;
                const int zz = row0 >> 11;
                const int rr = row0 & 2047;
                const float bv = bias[col];
                f16x4 o;
                #pragma unroll
                for (int r = 0; r < 4; ++r) o[r] = (f16)(acc[fm][fn][r] + bv);
                *(f16x4*)(outH + ((size_t)zz * N + col) * 2048 + rr) = o;
            }
        }
    } else {
        // swapped: lane rl walks M-row, reg r walks N-col -> vector stores
        const float* xaddz = xadd;
        float* outFz = outF;
        if (EPI == 3) {
            outFz += (size_t)z * batchC;
            xaddz += (size_t)z * batchC;
        }
        #pragma unroll
        for (int fm = 0; fm < 4; ++fm) {
            const int row = m0 + wr * 64 + fm * 16 + rl;
            #pragma unroll
            for (int fn = 0; fn < 4; ++fn) {
                const int colb = n0 + wc * 64 + fn * 16 + g * 4;
                if (EPI == 0) {
                    const float4 bv = *(const float4*)&bias[colb];
                    f16x4 o;
                    o[0] = (f16)gelu_exact(acc[fm][fn][0] + bv.x);
                    o[1] = (f16)gelu_exact(acc[fm][fn][1] + bv.y);
                    o[2] = (f16)gelu_exact(acc[fm][fn][2] + bv.z);
                    o[3] = (f16)gelu_exact(acc[fm][fn][3] + bv.w);
                    *(f16x4*)(outH + (size_t)row * N + colb) = o;
                } else {
                    const size_t idx = (size_t)row * N + colb;
                    const float4 xa = *(const float4*)&xaddz[idx];
                    float4 o;
                    o.x = acc[fm][fn][0] + xa.x;
                    o.y = acc[fm][fn][1] + xa.y;
                    o.z = acc[fm][fn][2] + xa.z;
                    o.w = acc[fm][fn][3] + xa.w;
                    *(float4*)(outFz + idx) = o;
                }
            }
        }
    }
}

// ---------------- GEMM (NT) 128^2 ring-3, swapped epilogue (g2) ------------
__global__ __launch_bounds__(256, 3)
void gemm_nt_kernel(const f16* __restrict__ A, const f16* __restrict__ Bt,
                    f16* __restrict__ outH,
                    int M, int N, int K,
                    long long batchA, long long batchB, long long batchC) {
    __shared__ __attribute__((aligned(16))) f16 sA[3][128 * 32];
    __shared__ __attribute__((aligned(16))) f16 sB[3][128 * 32];

    const int z = blockIdx.z;
    A  += (size_t)z * batchA;
    Bt += (size_t)z * batchB;

    const int m0 = blockIdx.x * 128;
    const int n0 = blockIdx.y * 128;
    const int t = threadIdx.x;
    const int l = t & 63;
    const int wid = t >> 6;
    const int wm = (wid >> 1) * 64;
    const int wn = (wid & 1) * 64;

    f32x4 acc[4][4] = {};

    const int rl = l & 15;
    const int nk = K >> 5;

    const int row0 = t >> 2;
    const int kb = ((t & 3) ^ (row0 & 3)) * 8;
    const f16* Ag0 = A  + (size_t)(m0 + row0) * K + kb;
    const f16* Ag1 = A  + (size_t)(m0 + row0 + 64) * K + kb;
    const f16* Bg0 = Bt + (size_t)(n0 + row0) * K + kb;
    const f16* Bg1 = Bt + (size_t)(n0 + row0 + 64) * K + kb;
    const int lo0 = wid * 512;
    const int lo1 = 2048 + wid * 512;

    const int swk = (((l >> 4) ^ (rl & 3))) * 8;

    gload_lds16(Ag0,      sA[0] + lo0);
    gload_lds16(Ag1,      sA[0] + lo1);
    gload_lds16(Bg0,      sB[0] + lo0);
    gload_lds16(Bg1,      sB[0] + lo1);
    gload_lds16(Ag0 + 32, sA[1] + lo0);
    gload_lds16(Ag1 + 32, sA[1] + lo1);
    gload_lds16(Bg0 + 32, sB[1] + lo0);
    gload_lds16(Bg1 + 32, sB[1] + lo1);

    f16 *curA = sA[0], *nxtA = sA[1], *farA = sA[2];
    f16 *curB = sB[0], *nxtB = sB[1], *farB = sB[2];

    for (int kt = 0; kt < nk; ++kt) {
        asm volatile("s_waitcnt vmcnt(4)" ::: "memory");
        __builtin_amdgcn_s_barrier();

        const int ktn = (kt + 2 < nk) ? kt + 2 : nk - 1;
        const int kof = ktn * 32;
        gload_lds16(Ag0 + kof, farA + lo0);
        gload_lds16(Ag1 + kof, farA + lo1);
        gload_lds16(Bg0 + kof, farB + lo0);
        gload_lds16(Bg1 + kof, farB + lo1);

        f16x8 a[4], b[4];
        #pragma unroll
        for (int f = 0; f < 4; ++f) {
            a[f] = *(const f16x8*)&curA[(wm + f * 16 + rl) * 32 + swk];
            b[f] = *(const f16x8*)&curB[(wn + f * 16 + rl) * 32 + swk];
        }
        // swapped: acc reg walks N
        #pragma unroll
        for (int fm = 0; fm < 4; ++fm)
            #pragma unroll
            for (int fn = 0; fn < 4; ++fn)
                acc[fm][fn] = __builtin_amdgcn_mfma_f32_16x16x32_f16(
                    b[fn], a[fm], acc[fm][fn], 0, 0, 0);

        f16* tA = curA; curA = nxtA; nxtA = farA; farA = tA;
        f16* tB = curB; curB = nxtB; nxtB = farB; farB = tB;
    }
    asm volatile("s_waitcnt vmcnt(0)" ::: "memory");

    const int rh = l >> 4;
    f16* outHz = outH + (size_t)z * batchC;
    #pragma unroll
    for (int fm = 0; fm < 4; ++fm) {
        const int row = m0 + wm + fm * 16 + rl;
        #pragma unroll
        for (int fn = 0; fn < 4; ++fn) {
            const int colb = n0 + wn + fn * 16 + rh * 4;
            f16x4 o;
            #pragma unroll
            for (int r = 0; r < 4; ++r) o[r] = (f16)acc[fm][fn][r];
            *(f16x4*)(outHz + (size_t)row * N + colb) = o;
        }
    }
}

extern "C" void kernel_launch(void* const* d_in, const int* in_sizes, int n_in,
                              void* d_out, int out_size, void* d_ws, size_t ws_size,
                              hipStream_t stream) {
    const float* x     = (const float*)d_in[0];
    const float* gamma = (const float*)d_in[1];
    const float* beta  = (const float*)d_in[2];
    const float* w1    = (const float*)d_in[3];
    const float* b1    = (const float*)d_in[4];
    const float* w2    = (const float*)d_in[5];
    const float* b2    = (const float*)d_in[6];
    float* out = (float*)d_out;

    const int BS = 4, T = 2048, DIM = 1024, HID = 2048;
    const int M = BS * T;  // 8192
    const long long MB = 1024 * 1024;

    // workspace layout (112 MiB total)
    char* ws = (char*)d_ws;
    f16*   x_h  = (f16*)(ws + 0 * MB);    // 16 MiB [M][DIM]
    f16*   y_h  = (f16*)(ws + 16 * MB);   // 16 MiB [M][DIM]
    f16*   h    = (f16*)(ws + 32 * MB);   // 32 MiB [M][HID]
    float* pre  = (float*)h;              // alias: h dead after GEMM2
    f16*   y2t  = (f16*)(ws + 64 * MB);   // 16 MiB [BS][DIM][T]
    f16*   x_t  = (f16*)(ws + 80 * MB);   // 16 MiB [BS][DIM][T]
    f16*   G    = (f16*)(ws + 96 * MB);   // 8 MiB  [BS][DIM][DIM]
    f16*   w1t  = (f16*)(ws + 104 * MB);  // 4 MiB  [HID][DIM]
    f16*   w2t  = (f16*)(ws + 108 * MB);  // 4 MiB  [DIM][HID]

    // 1) first LN + fp16 casts
    ln_cast_kernel<<<M, 256, 0, stream>>>(x, gamma, beta, y_h, x_h);

    // 2) weight transposes to fp16 [N][K]
    transpose_cast_kernel<<<dim3(HID / 32, DIM / 32), 256, 0, stream>>>(w1, w1t, DIM, HID);
    transpose_cast_kernel<<<dim3(DIM / 32, HID / 32), 256, 0, stream>>>(w2, w2t, HID, DIM);

    // 3) h = gelu(y @ w1 + b1)   [M][HID]  -- 256x128 ring-3, swapped epi
    gemm256x128_nt_kernel<0><<<dim3(M / 256, HID / 128, 1), 512, 0, stream>>>(
        y_h, w1t, b1, nullptr, h, nullptr, M, HID, DIM, 0, 0, 0);

    // 4) y2t[z][f][t] = (h @ w2 + b2)[z*T+t][f]  -- 256x128, transposed epi
    gemm256x128_nt_kernel<1><<<dim3(M / 256, DIM / 128, 1), 512, 0, stream>>>(
        h, w2t, b2, nullptr, y2t, nullptr, M, DIM, HID, 0, 0, 0);

    // 5) x_t[z][f][t] = x_h[z*T+t][f]
    transpose_f16_kernel<<<dim3(DIM / 32, T / 32, BS), 256, 0, stream>>>(x_h, x_t, T, DIM);

    // 6) G'[z][f2][f1] = sum_t y2t[z][f2][t] * x_t[z][f1][t]  -- 128^2 ring-3
    gemm_nt_kernel<<<dim3(DIM / 128, DIM / 128, BS), 256, 0, stream>>>(
        y2t, x_t, G, DIM, DIM, T,
        (long long)DIM * T, (long long)DIM * T, (long long)DIM * DIM);

    // 7) pre[z][t][f] = sum_k x_h[z][t][k] * G'[z][f][k] + x  -- 256x128
    gemm256x128_nt_kernel<3><<<dim3(T / 256, DIM / 128, BS), 512, 0, stream>>>(
        x_h, G, nullptr, x, nullptr, pre, T, DIM, DIM,
        (long long)T * DIM, (long long)DIM * DIM, (long long)T * DIM);

    // 8) final LN
    ln_final_kernel<<<M, 256, 0, stream>>>(pre, gamma, beta, out);
}